// Round 4
// baseline (2383.092 us; speedup 1.0000x reference)
//
#include <hip/hip_runtime.h>

#define NSTEP 10

// ---------------------------------------------------------------------------
// Prep: transpose W1 [256][250] -> W1T [250][256], W2 [128][256] -> W2T [256][128]
// ---------------------------------------------------------------------------
extern "C" __global__ void __launch_bounds__(256) snn_prep(
    const float* __restrict__ W1, const float* __restrict__ W2,
    float* __restrict__ W1T, float* __restrict__ W2T)
{
    int i0 = blockIdx.x * 256 + threadIdx.x;
    int stride = gridDim.x * 256;
    for (int idx = i0; idx < 250 * 256; idx += stride) {
        int k = idx >> 8;
        int n = idx & 255;
        W1T[idx] = W1[n * 250 + k];
    }
    for (int idx = i0; idx < 256 * 128; idx += stride) {
        int k = idx >> 7;
        int j = idx & 127;
        W2T[idx] = W2[j * 256 + k];
    }
}

// ---------------------------------------------------------------------------
// Main fused SNN kernel. 64 samples/block, 512 threads, 10 steps fused.
//
// R4 design: R3's no-spill per-thread state (cur1 32 + m1 32 + m2 16 + a2 16
// ~= 110 live < 128 VGPR) kept EXACTLY, but:
//  - 512-thread blocks halve W2T L2 stream traffic and give 8 waves/block
//  - u8 spikes shrink LDS to 37.4 KB -> 2 blocks/CU = 16 waves/CU (~50% occ,
//    2x R3) to hide the ~200-cycle L2 latency of direct W2T reads
//  - unroll 8 on the k loop for >=8 outstanding global loads per wave
//
// Thread maps:
//   L1/prologue: nt=t&15 (16 neurons n0=nt*16), st=t>>4 (0..31, 2 samples s0a=2*st)
//   L2 GEMM:     jt=t&31 (4 j at jt*4),         sg=t>>5 (0..15, 4 samples s0b=4*sg)
//   L3 partials: t<256: jr=t>>6 (32-j chunk), sl=t&63
//   L3 LIF:      t<320: o=t>>6, sl=t&63
//
// Spike swizzle (byte-granular, XOR-bijective, alignment-safe):
//   s1: col = s ^ (8*((row>>4)&7))   (writer nt = row>>4)
//   s2: col = s ^ (8*((row>>2)&7))   (writer jt = row>>2)
//
// LDS layout (bytes):
//   [0,18432)      s1Lb u8[256][72]
//   [18432,27648)  s2Lb u8[128][72]
//   [27648,31744)  W3L  f32[128][8]
//   [31744,36864)  pL   f32[20][64]
//   [36864,37408)  bL   f32[133]  (b2[128] ++ b3[5])
// Total 37408 B -> 2 blocks/CU (74.8 KB of 160 KB), 16 waves/CU.
// ---------------------------------------------------------------------------
extern "C" __global__ void __launch_bounds__(512, 4) snn_main(
    const float* __restrict__ x,
    const float* __restrict__ b1,
    const float* __restrict__ b2g,
    const float* __restrict__ W3,
    const float* __restrict__ b3,
    const float* __restrict__ W1T,
    const float* __restrict__ W2T,
    float* __restrict__ out)
{
    __shared__ __align__(16) char ldsraw[37408];
    unsigned char* s1Lb = (unsigned char*)(ldsraw);
    unsigned char* s2Lb = (unsigned char*)(ldsraw + 18432);
    float* W3L = (float*)(ldsraw + 27648);
    float* pL  = (float*)(ldsraw + 31744);
    float* bL  = (float*)(ldsraw + 36864);

    const int t   = threadIdx.x;
    const int nt  = t & 15;
    const int st  = t >> 4;          // 0..31
    const int s0a = st * 2;
    const int n0  = nt * 16;
    const int jt  = t & 31;
    const int sg  = t >> 5;          // 0..15
    const int s0b = sg * 4;
    const int sBase = blockIdx.x * 64;

    // ---- stage W3 (transposed, padded to 8) + biases ----
    for (int idx = t; idx < 640; idx += 512) {
        int o = idx >> 7;            // W3 is [5][128]
        int j = idx & 127;
        W3L[j * 8 + o] = W3[idx];
    }
    if (t < 128) bL[t] = b2g[t];
    if (t < 5)   bL[128 + t] = b3[t];

    // ---- cur1 = x @ W1.T, direct global reads (identical chain to R3) ----
    float cur1[16][2];
    #pragma unroll
    for (int i = 0; i < 16; ++i) { cur1[i][0] = 0.0f; cur1[i][1] = 0.0f; }

    const float* xr0 = x + (sBase + s0a) * 250;
    const float* xr1 = xr0 + 250;
    #pragma unroll 2
    for (int k = 0; k < 250; ++k) {
        const float x0 = xr0[k];
        const float x1 = xr1[k];
        float w[16];
        *(float4*)&w[0]  = *(const float4*)&W1T[k * 256 + n0];
        *(float4*)&w[4]  = *(const float4*)&W1T[k * 256 + n0 + 4];
        *(float4*)&w[8]  = *(const float4*)&W1T[k * 256 + n0 + 8];
        *(float4*)&w[12] = *(const float4*)&W1T[k * 256 + n0 + 12];
        #pragma unroll
        for (int i = 0; i < 16; ++i) {
            cur1[i][0] = fmaf(w[i], x0, cur1[i][0]);
            cur1[i][1] = fmaf(w[i], x1, cur1[i][1]);
        }
    }
    {
        float bb[16];
        *(float4*)&bb[0]  = *(const float4*)&b1[n0];
        *(float4*)&bb[4]  = *(const float4*)&b1[n0 + 4];
        *(float4*)&bb[8]  = *(const float4*)&b1[n0 + 8];
        *(float4*)&bb[12] = *(const float4*)&b1[n0 + 12];
        #pragma unroll
        for (int i = 0; i < 16; ++i) {
            cur1[i][0] = __fadd_rn(cur1[i][0], bb[i]);
            cur1[i][1] = __fadd_rn(cur1[i][1], bb[i]);
        }
    }

    __syncthreads();   // W3L/bL staged

    // ---- persistent state ----
    float m1[16][2];
    #pragma unroll
    for (int i = 0; i < 16; ++i) { m1[i][0] = 0.0f; m1[i][1] = 0.0f; }
    float m2[4][4];
    #pragma unroll
    for (int jj = 0; jj < 4; ++jj)
        #pragma unroll
        for (int ss = 0; ss < 4; ++ss) m2[jj][ss] = 0.0f;
    float m3 = 0.0f, acc3 = 0.0f;

    const int keyA = (nt & 7) << 3;   // write swizzle for this thread's s1 rows
    const int keyC = (jt & 7) << 3;   // write swizzle for this thread's s2 rows

    for (int stp = 0; stp < NSTEP; ++stp) {
        // ========== A: layer-1 LIF + u8 spikes -> LDS (swizzled) ==========
        #pragma unroll
        for (int i = 0; i < 16; ++i) {
            unsigned int pk = 0;
            {
                float m = m1[i][0];
                float r = (m > 1.0f) ? 1.0f : 0.0f;
                m = __fsub_rn(__fadd_rn(__fmul_rn(0.9f, m), cur1[i][0]), r);
                m1[i][0] = m;
                if (m > 1.0f) pk |= 1u;
            }
            {
                float m = m1[i][1];
                float r = (m > 1.0f) ? 1.0f : 0.0f;
                m = __fsub_rn(__fadd_rn(__fmul_rn(0.9f, m), cur1[i][1]), r);
                m1[i][1] = m;
                if (m > 1.0f) pk |= 1u << 8;
            }
            *(unsigned short*)&s1Lb[(n0 + i) * 72 + (s0a ^ keyA)] =
                (unsigned short)pk;
        }
        __syncthreads();   // bar1: s1 ready

        // ========== B: cur2 = s1 @ W2.T, W2T direct from global ==========
        float a2[4][4];
        #pragma unroll
        for (int jj = 0; jj < 4; ++jj)
            #pragma unroll
            for (int ss = 0; ss < 4; ++ss) a2[jj][ss] = 0.0f;

        #pragma unroll 8
        for (int k = 0; k < 256; ++k) {
            const float4 w = *(const float4*)&W2T[k * 128 + jt * 4];
            const unsigned int sp = *(const unsigned int*)
                &s1Lb[k * 72 + (s0b ^ (((k >> 4) & 7) << 3))];
            float fsv[4];
            fsv[0] = (float)(sp & 0xFFu);
            fsv[1] = (float)((sp >> 8) & 0xFFu);
            fsv[2] = (float)((sp >> 16) & 0xFFu);
            fsv[3] = (float)(sp >> 24);
            const float* wv = &w.x;
            #pragma unroll
            for (int jj = 0; jj < 4; ++jj)
                #pragma unroll
                for (int ss = 0; ss < 4; ++ss)
                    a2[jj][ss] = fmaf(wv[jj], fsv[ss], a2[jj][ss]);
        }

        // ========== C: layer-2 LIF + u8 spikes -> LDS ==========
        #pragma unroll
        for (int jj = 0; jj < 4; ++jj) {
            const int j = jt * 4 + jj;
            const float bj = bL[j];
            unsigned int pk = 0;
            #pragma unroll
            for (int ss = 0; ss < 4; ++ss) {
                float c2 = __fadd_rn(a2[jj][ss], bj);
                float m = m2[jj][ss];
                float r = (m > 1.0f) ? 1.0f : 0.0f;
                m = __fsub_rn(__fadd_rn(__fmul_rn(0.9f, m), c2), r);
                m2[jj][ss] = m;
                if (m > 1.0f) pk |= 1u << (8 * ss);
            }
            *(unsigned int*)&s2Lb[j * 72 + (s0b ^ keyC)] = pk;
        }
        __syncthreads();   // bar2: s2 ready

        // ========== D: layer-3 partial dots (4-way j split) ==========
        if (t < 256) {
            const int sl = t & 63;
            const int jr = t >> 6;
            float part[5] = {0.0f, 0.0f, 0.0f, 0.0f, 0.0f};
            #pragma unroll 8
            for (int jj = 0; jj < 32; ++jj) {
                const int j = jr * 32 + jj;
                const float s2v =
                    (float)s2Lb[j * 72 + (sl ^ (((j >> 2) & 7) << 3))];
                const float4 w3a = *(const float4*)&W3L[j * 8];
                const float  w3e = W3L[j * 8 + 4];
                part[0] = fmaf(w3a.x, s2v, part[0]);
                part[1] = fmaf(w3a.y, s2v, part[1]);
                part[2] = fmaf(w3a.z, s2v, part[2]);
                part[3] = fmaf(w3a.w, s2v, part[3]);
                part[4] = fmaf(w3e,   s2v, part[4]);
            }
            #pragma unroll
            for (int o = 0; o < 5; ++o)
                pL[(o * 4 + jr) * 64 + sl] = part[o];
        }
        __syncthreads();   // bar3: partials ready

        // ========== E: layer-3 LIF + spike count ==========
        if (t < 320) {
            const int o  = t >> 6;
            const int sl = t & 63;
            float c3 = pL[(o * 4 + 0) * 64 + sl];
            c3 += pL[(o * 4 + 1) * 64 + sl];
            c3 += pL[(o * 4 + 2) * 64 + sl];
            c3 += pL[(o * 4 + 3) * 64 + sl];
            c3 = __fadd_rn(c3, bL[128 + o]);
            float m = m3;
            float r = (m > 1.0f) ? 1.0f : 0.0f;
            m = __fsub_rn(__fadd_rn(__fmul_rn(0.9f, m), c3), r);
            m3 = m;
            if (m > 1.0f) acc3 += 1.0f;
        }
    }

    // ---- epilogue ----
    if (t < 320) {
        out[(sBase + (t & 63)) * 5 + (t >> 6)] = acc3;
    }
}

extern "C" void kernel_launch(void* const* d_in, const int* in_sizes, int n_in,
                              void* d_out, int out_size, void* d_ws, size_t ws_size,
                              hipStream_t stream) {
    const float* x  = (const float*)d_in[0];
    const float* W1 = (const float*)d_in[1];
    const float* b1 = (const float*)d_in[2];
    const float* W2 = (const float*)d_in[3];
    const float* b2 = (const float*)d_in[4];
    const float* W3 = (const float*)d_in[5];
    const float* b3 = (const float*)d_in[6];
    float* out = (float*)d_out;

    float* W1T = (float*)d_ws;            // 250*256 floats
    float* W2T = W1T + 250 * 256;         // 256*128 floats

    const int B = in_sizes[0] / 250;      // 131072
    const int nwg = B / 64;               // 2048

    snn_prep<<<128, 256, 0, stream>>>(W1, W2, W1T, W2T);
    snn_main<<<nwg, 512, 0, stream>>>(x, b1, b2, W3, b3, W1T, W2T, out);
}

// Round 5
// 1369.745 us; speedup vs baseline: 1.7398x; 1.7398x over previous
//
#include <hip/hip_runtime.h>

#define NSTEP 10

typedef __attribute__((ext_vector_type(8))) short bf16x8;   // 8 bf16 = 4 VGPRs
typedef __attribute__((ext_vector_type(4))) float f32x4;    // MFMA C/D

// ---------------------------------------------------------------------------
// Prep 1: transpose W1 [256][250] -> W1T [250][256]
// ---------------------------------------------------------------------------
extern "C" __global__ void __launch_bounds__(256) snn_prep(
    const float* __restrict__ W1, float* __restrict__ W1T)
{
    int i0 = blockIdx.x * 256 + threadIdx.x;
    int stride = gridDim.x * 256;
    for (int idx = i0; idx < 250 * 256; idx += stride) {
        int k = idx >> 8;
        int n = idx & 255;
        W1T[idx] = W1[n * 250 + k];
    }
}

// ---------------------------------------------------------------------------
// Prep 2: exact 3-way bf16 split of W2 into MFMA B-fragment layout.
//   w = h1 + h2 + h3 EXACTLY (RNE bf16 splits; residuals exactly representable).
//   Fragment layout for mfma_f32_16x16x32_bf16 B-operand:
//     lane l supplies B[k][n] with n = l&15, k = slab*32 + (l>>4)*8 + e.
//   Buffer: [wave j-strip 0..7][split 0..2][slab 0..7][lane 0..63][8 bf16]
//   so the main kernel's per-(split,slab) load is one coalesced dwordx4/lane.
// ---------------------------------------------------------------------------
__device__ __forceinline__ unsigned int bf16_rne_hi(float f) {
    unsigned int u = __float_as_uint(f);
    return (u + 0x7FFFu + ((u >> 16) & 1u)) & 0xFFFF0000u;
}

extern "C" __global__ void __launch_bounds__(256) snn_prep2(
    const float* __restrict__ W2, unsigned short* __restrict__ W2F)
{
    int idx = blockIdx.x * 256 + threadIdx.x;   // 8*3*8*64 = 12288 work items
    if (idx >= 8 * 3 * 8 * 64) return;
    int lane  = idx & 63;
    int slab  = (idx >> 6) & 7;
    int split = (idx >> 9) % 3;
    int w     = idx / (3 * 8 * 64);
    int j  = w * 16 + (lane & 15);
    int k0 = slab * 32 + (lane >> 4) * 8;
    unsigned short res[8];
    #pragma unroll
    for (int e = 0; e < 8; ++e) {
        float wval = W2[j * 256 + k0 + e];
        unsigned int u1 = bf16_rne_hi(wval);
        float h1 = __uint_as_float(u1);
        float r1 = __fsub_rn(wval, h1);          // exact
        unsigned int u2 = bf16_rne_hi(r1);
        float h2 = __uint_as_float(u2);
        float r2 = __fsub_rn(r1, h2);            // exact, bf16-representable
        unsigned int u3 = bf16_rne_hi(r2);       // exact (<=8 sig bits left)
        unsigned int sel = (split == 0) ? u1 : (split == 1) ? u2 : u3;
        res[e] = (unsigned short)(sel >> 16);
    }
    *(uint4*)&W2F[(((w * 3 + split) * 8 + slab) << 9) + lane * 8] =
        *(uint4*)res;
}

// ---------------------------------------------------------------------------
// Main fused SNN kernel. 64 samples/block, 512 threads, 10 steps fused.
//
// R5: phase B (layer-2 GEMM, 80% of FLOPs) moved to MFMA via exact 3-way
// bf16 split of W2 (order-only numeric deviation, same class as R1-R4 which
// all matched bit-exactly). Everything else is R4's passing code.
//
// Thread maps:
//   prologue/A: nt=t&15 (16 neurons n0=nt*16), st=t>>4 (2 samples s0a=2*st)
//   B (MFMA):   wv=t>>6 (j-strip 16*wv), lane=t&63; 4 m-tiles of 16 samples;
//               acc[mt][reg] -> sample = mt*16 + (lane>>4)*4 + reg, j = wv*16+(lane&15)
//   D: t<256: jr=t>>6 (32-j chunk), sl=t&63   (identical to R4)
//   E: t<320: o=t>>6, sl=t&63                 (identical to R4)
//
// s1 spikes: bf16 rows [64 samples][256 k], 512 B/row, 16B-chunk XOR swizzle
//   phys_chunk = chunk ^ (row&7)  -> fragment ds_read_b128 2-way conflicts (free).
// s2 spikes: u8 [128][72] with R4's swizzle (phase C writer changed, D reader same).
//
// LDS (bytes): s1bf [0,32768) | s2Lb [32768,41984) | W3L [41984,46080)
//              pL [46080,51200) | bL [51200,51736)   total 51760.
// ---------------------------------------------------------------------------
extern "C" __global__ void __launch_bounds__(512, 2) snn_main(
    const float* __restrict__ x,
    const float* __restrict__ b1,
    const float* __restrict__ b2g,
    const float* __restrict__ W3,
    const float* __restrict__ b3,
    const float* __restrict__ W1T,
    const unsigned short* __restrict__ W2F,
    float* __restrict__ out)
{
    __shared__ __align__(16) char ldsraw[51760];
    char* s1bf = ldsraw;                                // [64][512B] bf16
    unsigned char* s2Lb = (unsigned char*)(ldsraw + 32768);  // [128][72] u8
    float* W3L = (float*)(ldsraw + 41984);              // [128][8]
    float* pL  = (float*)(ldsraw + 46080);              // [20][64]
    float* bL  = (float*)(ldsraw + 51200);              // [133]

    const int t    = threadIdx.x;
    const int nt   = t & 15;
    const int st   = t >> 4;          // 0..31
    const int s0a  = st * 2;
    const int n0   = nt * 16;
    const int lane = t & 63;
    const int wv   = t >> 6;          // 0..7 (j-strip)
    const int l15  = lane & 15;
    const int lq   = lane >> 4;       // 0..3
    const int sBase = blockIdx.x * 64;

    // ---- stage W3 (transposed, padded to 8) + biases ----
    for (int idx = t; idx < 640; idx += 512) {
        int o = idx >> 7;             // W3 is [5][128]
        int j = idx & 127;
        W3L[j * 8 + o] = W3[idx];
    }
    if (t < 128) bL[t] = b2g[t];
    if (t < 5)   bL[128 + t] = b3[t];

    // ---- cur1 = x @ W1.T, direct global reads (identical chain to R4) ----
    float cur1[16][2];
    #pragma unroll
    for (int i = 0; i < 16; ++i) { cur1[i][0] = 0.0f; cur1[i][1] = 0.0f; }

    const float* xr0 = x + (sBase + s0a) * 250;
    const float* xr1 = xr0 + 250;
    #pragma unroll 2
    for (int k = 0; k < 250; ++k) {
        const float x0 = xr0[k];
        const float x1 = xr1[k];
        float w[16];
        *(float4*)&w[0]  = *(const float4*)&W1T[k * 256 + n0];
        *(float4*)&w[4]  = *(const float4*)&W1T[k * 256 + n0 + 4];
        *(float4*)&w[8]  = *(const float4*)&W1T[k * 256 + n0 + 8];
        *(float4*)&w[12] = *(const float4*)&W1T[k * 256 + n0 + 12];
        #pragma unroll
        for (int i = 0; i < 16; ++i) {
            cur1[i][0] = fmaf(w[i], x0, cur1[i][0]);
            cur1[i][1] = fmaf(w[i], x1, cur1[i][1]);
        }
    }
    {
        float bb[16];
        *(float4*)&bb[0]  = *(const float4*)&b1[n0];
        *(float4*)&bb[4]  = *(const float4*)&b1[n0 + 4];
        *(float4*)&bb[8]  = *(const float4*)&b1[n0 + 8];
        *(float4*)&bb[12] = *(const float4*)&b1[n0 + 12];
        #pragma unroll
        for (int i = 0; i < 16; ++i) {
            cur1[i][0] = __fadd_rn(cur1[i][0], bb[i]);
            cur1[i][1] = __fadd_rn(cur1[i][1], bb[i]);
        }
    }

    __syncthreads();   // W3L/bL staged

    // ---- persistent state ----
    float m1[16][2];
    #pragma unroll
    for (int i = 0; i < 16; ++i) { m1[i][0] = 0.0f; m1[i][1] = 0.0f; }
    float m2[4][4];                   // [m-tile][reg]
    #pragma unroll
    for (int mt = 0; mt < 4; ++mt)
        #pragma unroll
        for (int rg = 0; rg < 4; ++rg) m2[mt][rg] = 0.0f;
    float m3 = 0.0f, acc3 = 0.0f;

    const unsigned short* fb = W2F + (wv * 24) * 512 + lane * 8;
    const int keyB   = (lane & 7) << 4;   // s1 fragment-read swizzle key
    const int chunkq = lq << 4;
    const int jC     = wv * 16 + l15;     // this lane's layer-2 neuron
    const int keyC2  = ((jC >> 2) & 7) << 3;

    #pragma unroll 1
    for (int stp = 0; stp < NSTEP; ++stp) {
        // ========== A: layer-1 LIF + bf16 spikes -> LDS (chunk-swizzled) =====
        {
            unsigned int dwa[2][8];
            #pragma unroll
            for (int i = 0; i < 16; ++i) {
                #pragma unroll
                for (int s = 0; s < 2; ++s) {
                    float m = m1[i][s];
                    float r = (m > 1.0f) ? 1.0f : 0.0f;
                    m = __fsub_rn(__fadd_rn(__fmul_rn(0.9f, m), cur1[i][s]), r);
                    m1[i][s] = m;
                    unsigned int bits = (m > 1.0f) ? 0x3F80u : 0u;  // bf16 1.0
                    if (i & 1) dwa[s][i >> 1] |= bits << 16;
                    else       dwa[s][i >> 1]  = bits;
                }
            }
            #pragma unroll
            for (int s = 0; s < 2; ++s) {
                const int row = s0a + s;
                const int key = row & 7;
                char* rp = s1bf + row * 512;
                uint4 lo = make_uint4(dwa[s][0], dwa[s][1], dwa[s][2], dwa[s][3]);
                uint4 hi = make_uint4(dwa[s][4], dwa[s][5], dwa[s][6], dwa[s][7]);
                *(uint4*)(rp + (((2 * nt + 0) ^ key) << 4)) = lo;
                *(uint4*)(rp + (((2 * nt + 1) ^ key) << 4)) = hi;
            }
        }
        __syncthreads();   // bar1: s1 ready

        // ========== B: cur2 = s1 @ W2.T via MFMA (3-split, h3->h2->h1) ======
        f32x4 acc[4];
        {
            const f32x4 z = {0.0f, 0.0f, 0.0f, 0.0f};
            acc[0] = z; acc[1] = z; acc[2] = z; acc[3] = z;
        }
        #pragma unroll
        for (int slab = 0; slab < 8; ++slab) {
            const bf16x8 B2 = *(const bf16x8*)(fb + (16 + slab) * 512); // h3
            const bf16x8 B1 = *(const bf16x8*)(fb + (8  + slab) * 512); // h2
            const bf16x8 B0 = *(const bf16x8*)(fb + (0  + slab) * 512); // h1
            const int coff = (slab * 64 + chunkq) ^ keyB;
            const bf16x8 A0 = *(const bf16x8*)(s1bf + (l15     ) * 512 + coff);
            const bf16x8 A1 = *(const bf16x8*)(s1bf + (l15 + 16) * 512 + coff);
            const bf16x8 A2 = *(const bf16x8*)(s1bf + (l15 + 32) * 512 + coff);
            const bf16x8 A3 = *(const bf16x8*)(s1bf + (l15 + 48) * 512 + coff);
            acc[0] = __builtin_amdgcn_mfma_f32_16x16x32_bf16(A0, B2, acc[0], 0, 0, 0);
            acc[1] = __builtin_amdgcn_mfma_f32_16x16x32_bf16(A1, B2, acc[1], 0, 0, 0);
            acc[2] = __builtin_amdgcn_mfma_f32_16x16x32_bf16(A2, B2, acc[2], 0, 0, 0);
            acc[3] = __builtin_amdgcn_mfma_f32_16x16x32_bf16(A3, B2, acc[3], 0, 0, 0);
            acc[0] = __builtin_amdgcn_mfma_f32_16x16x32_bf16(A0, B1, acc[0], 0, 0, 0);
            acc[1] = __builtin_amdgcn_mfma_f32_16x16x32_bf16(A1, B1, acc[1], 0, 0, 0);
            acc[2] = __builtin_amdgcn_mfma_f32_16x16x32_bf16(A2, B1, acc[2], 0, 0, 0);
            acc[3] = __builtin_amdgcn_mfma_f32_16x16x32_bf16(A3, B1, acc[3], 0, 0, 0);
            acc[0] = __builtin_amdgcn_mfma_f32_16x16x32_bf16(A0, B0, acc[0], 0, 0, 0);
            acc[1] = __builtin_amdgcn_mfma_f32_16x16x32_bf16(A1, B0, acc[1], 0, 0, 0);
            acc[2] = __builtin_amdgcn_mfma_f32_16x16x32_bf16(A2, B0, acc[2], 0, 0, 0);
            acc[3] = __builtin_amdgcn_mfma_f32_16x16x32_bf16(A3, B0, acc[3], 0, 0, 0);
        }

        // ========== C: layer-2 LIF + u8 spikes -> LDS (R4 reader layout) ====
        {
            const float bj = bL[jC];
            #pragma unroll
            for (int mt = 0; mt < 4; ++mt) {
                unsigned int pk = 0;
                #pragma unroll
                for (int rg = 0; rg < 4; ++rg) {
                    float c2 = __fadd_rn(acc[mt][rg], bj);
                    float m = m2[mt][rg];
                    float r = (m > 1.0f) ? 1.0f : 0.0f;
                    m = __fsub_rn(__fadd_rn(__fmul_rn(0.9f, m), c2), r);
                    m2[mt][rg] = m;
                    if (m > 1.0f) pk |= 1u << (8 * rg);
                }
                const int smp0 = mt * 16 + lq * 4;   // 4-aligned sample base
                *(unsigned int*)&s2Lb[jC * 72 + (smp0 ^ keyC2)] = pk;
            }
        }
        __syncthreads();   // bar2: s2 ready

        // ========== D: layer-3 partial dots (identical to R4) ==========
        if (t < 256) {
            const int sl = t & 63;
            const int jr = t >> 6;
            float part[5] = {0.0f, 0.0f, 0.0f, 0.0f, 0.0f};
            #pragma unroll 8
            for (int jj = 0; jj < 32; ++jj) {
                const int j = jr * 32 + jj;
                const float s2v =
                    (float)s2Lb[j * 72 + (sl ^ (((j >> 2) & 7) << 3))];
                const float4 w3a = *(const float4*)&W3L[j * 8];
                const float  w3e = W3L[j * 8 + 4];
                part[0] = fmaf(w3a.x, s2v, part[0]);
                part[1] = fmaf(w3a.y, s2v, part[1]);
                part[2] = fmaf(w3a.z, s2v, part[2]);
                part[3] = fmaf(w3a.w, s2v, part[3]);
                part[4] = fmaf(w3e,   s2v, part[4]);
            }
            #pragma unroll
            for (int o = 0; o < 5; ++o)
                pL[(o * 4 + jr) * 64 + sl] = part[o];
        }
        __syncthreads();   // bar3: partials ready

        // ========== E: layer-3 LIF + spike count (identical to R4) ==========
        if (t < 320) {
            const int o  = t >> 6;
            const int sl = t & 63;
            float c3 = pL[(o * 4 + 0) * 64 + sl];
            c3 += pL[(o * 4 + 1) * 64 + sl];
            c3 += pL[(o * 4 + 2) * 64 + sl];
            c3 += pL[(o * 4 + 3) * 64 + sl];
            c3 = __fadd_rn(c3, bL[128 + o]);
            float m = m3;
            float r = (m > 1.0f) ? 1.0f : 0.0f;
            m = __fsub_rn(__fadd_rn(__fmul_rn(0.9f, m), c3), r);
            m3 = m;
            if (m > 1.0f) acc3 += 1.0f;
        }
    }

    // ---- epilogue ----
    if (t < 320) {
        out[(sBase + (t & 63)) * 5 + (t >> 6)] = acc3;
    }
}

extern "C" void kernel_launch(void* const* d_in, const int* in_sizes, int n_in,
                              void* d_out, int out_size, void* d_ws, size_t ws_size,
                              hipStream_t stream) {
    const float* x  = (const float*)d_in[0];
    const float* W1 = (const float*)d_in[1];
    const float* b1 = (const float*)d_in[2];
    const float* W2 = (const float*)d_in[3];
    const float* b2 = (const float*)d_in[4];
    const float* W3 = (const float*)d_in[5];
    const float* b3 = (const float*)d_in[6];
    float* out = (float*)d_out;

    float* W1T = (float*)d_ws;                                  // 64000 f32
    unsigned short* W2F = (unsigned short*)((char*)d_ws + 256000); // 98304 bf16

    const int B = in_sizes[0] / 250;      // 131072
    const int nwg = B / 64;               // 2048

    snn_prep <<<64, 256, 0, stream>>>(W1, W1T);
    snn_prep2<<<48, 256, 0, stream>>>(W2, W2F);
    snn_main <<<nwg, 512, 0, stream>>>(x, b1, b2, W3, b3, W1T, W2F, out);
}

// Round 7
// 1282.195 us; speedup vs baseline: 1.8586x; 1.0683x over previous
//
#include <hip/hip_runtime.h>

#define NSTEP 10

typedef __attribute__((ext_vector_type(8))) short bf16x8;   // 8 bf16 = 4 VGPRs
typedef __attribute__((ext_vector_type(4))) float f32x4;    // MFMA C/D

// ---------------------------------------------------------------------------
// Prep 1: transpose W1 [256][250] -> W1T [250][256]
// ---------------------------------------------------------------------------
extern "C" __global__ void __launch_bounds__(256) snn_prep(
    const float* __restrict__ W1, float* __restrict__ W1T)
{
    int i0 = blockIdx.x * 256 + threadIdx.x;
    int stride = gridDim.x * 256;
    for (int idx = i0; idx < 250 * 256; idx += stride) {
        int k = idx >> 8;
        int n = idx & 255;
        W1T[idx] = W1[n * 250 + k];
    }
}

// ---------------------------------------------------------------------------
// Prep 2: exact 3-way bf16 split of W2 into MFMA B-fragment layout
// (identical to R5). [j-strip 0..7][split 0..2][slab 0..7][lane][8]  (192 KB)
// ---------------------------------------------------------------------------
__device__ __forceinline__ unsigned int bf16_rne_hi(float f) {
    unsigned int u = __float_as_uint(f);
    return (u + 0x7FFFu + ((u >> 16) & 1u)) & 0xFFFF0000u;
}

extern "C" __global__ void __launch_bounds__(256) snn_prep2(
    const float* __restrict__ W2, unsigned short* __restrict__ W2F)
{
    int idx = blockIdx.x * 256 + threadIdx.x;   // 8*3*8*64 = 12288 items
    if (idx >= 8 * 3 * 8 * 64) return;
    int lane  = idx & 63;
    int slab  = (idx >> 6) & 7;
    int split = (idx >> 9) % 3;
    int w     = idx / (3 * 8 * 64);
    int j  = w * 16 + (lane & 15);
    int k0 = slab * 32 + (lane >> 4) * 8;
    unsigned short res[8];
    #pragma unroll
    for (int e = 0; e < 8; ++e) {
        float wval = W2[j * 256 + k0 + e];
        unsigned int u1 = bf16_rne_hi(wval);
        float r1 = __fsub_rn(wval, __uint_as_float(u1));
        unsigned int u2 = bf16_rne_hi(r1);
        float r2 = __fsub_rn(r1, __uint_as_float(u2));
        unsigned int u3 = bf16_rne_hi(r2);
        unsigned int sel = (split == 0) ? u1 : (split == 1) ? u2 : u3;
        res[e] = (unsigned short)(sel >> 16);
    }
    *(uint4*)&W2F[(((w * 3 + split) * 8 + slab) << 9) + lane * 8] =
        *(uint4*)res;
}

// ---------------------------------------------------------------------------
// Main fused SNN kernel. 64 samples/block, 512 threads, 10 steps fused.
//
// R7 = R5 (passed, absmax 0.0) with ONE change: the prologue's x reads go
// through an LDS-staged transposed tile (xT[k][sample], coalesced dwordx4
// global loads, one ds_read_b64 per k) instead of 500 scalar global loads
// per thread. cur1's fmaf chain order is bit-identical to R5 (values come
// from the same x elements). Phases A-E byte-identical to R5. R6's lesson:
// NO arithmetic-order changes, only data movement.
//
// LDS (bytes): persistent layout as R5:
//   s1bf [0,32768) | s2Lb [32768,41984) | W3L [41984,46080)
//   pL [46080,51200) | bL [51200,51736)
// Prologue alias: xT f32[250][68] @0 (68000 B) - dead before anything else
// is written (staging of W3L/bL happens AFTER the cur1 chain).
// Total 68000 B -> 2 blocks/CU (136 KB of 160 KB), 16 waves/CU.
// ---------------------------------------------------------------------------
extern "C" __global__ void __launch_bounds__(512, 2) snn_main(
    const float* __restrict__ x,
    const float* __restrict__ b1,
    const float* __restrict__ b2g,
    const float* __restrict__ W3,
    const float* __restrict__ b3,
    const float* __restrict__ W1T,
    const unsigned short* __restrict__ W2F,
    float* __restrict__ out)
{
    __shared__ __align__(16) char ldsraw[68000];
    char* s1bf = ldsraw;                                     // [64][512B] bf16
    unsigned char* s2Lb = (unsigned char*)(ldsraw + 32768);  // [128][72] u8
    float* W3L = (float*)(ldsraw + 41984);                   // [128][8]
    float* pL  = (float*)(ldsraw + 46080);                   // [20][64]
    float* bL  = (float*)(ldsraw + 51200);                   // [133]
    float* xT  = (float*)(ldsraw);                           // prologue alias

    const int t    = threadIdx.x;
    const int nt   = t & 15;
    const int st   = t >> 4;          // 0..31
    const int s0a  = st * 2;
    const int n0   = nt * 16;
    const int lane = t & 63;
    const int wv   = t >> 6;          // 0..7 (j-strip)
    const int l15  = lane & 15;
    const int lq   = lane >> 4;       // 0..3
    const int sBase = blockIdx.x * 64;

    // ---- prologue step 1: stage x tile transposed into LDS (coalesced) ----
    for (int i = t; i < 64 * 250; i += 512) {
        int sl = i / 250;
        int kl = i - sl * 250;
        xT[kl * 68 + sl] = x[(sBase + sl) * 250 + kl];
    }
    __syncthreads();

    // ---- prologue step 2: cur1 = x @ W1.T (chain bit-identical to R5) ----
    float cur1[16][2];
    #pragma unroll
    for (int i = 0; i < 16; ++i) { cur1[i][0] = 0.0f; cur1[i][1] = 0.0f; }

    #pragma unroll 2
    for (int k = 0; k < 250; ++k) {
        const float2 xp = *(const float2*)&xT[k * 68 + s0a];
        const float x0 = xp.x;
        const float x1 = xp.y;
        float w[16];
        *(float4*)&w[0]  = *(const float4*)&W1T[k * 256 + n0];
        *(float4*)&w[4]  = *(const float4*)&W1T[k * 256 + n0 + 4];
        *(float4*)&w[8]  = *(const float4*)&W1T[k * 256 + n0 + 8];
        *(float4*)&w[12] = *(const float4*)&W1T[k * 256 + n0 + 12];
        #pragma unroll
        for (int i = 0; i < 16; ++i) {
            cur1[i][0] = fmaf(w[i], x0, cur1[i][0]);
            cur1[i][1] = fmaf(w[i], x1, cur1[i][1]);
        }
    }
    {
        float bb[16];
        *(float4*)&bb[0]  = *(const float4*)&b1[n0];
        *(float4*)&bb[4]  = *(const float4*)&b1[n0 + 4];
        *(float4*)&bb[8]  = *(const float4*)&b1[n0 + 8];
        *(float4*)&bb[12] = *(const float4*)&b1[n0 + 12];
        #pragma unroll
        for (int i = 0; i < 16; ++i) {
            cur1[i][0] = __fadd_rn(cur1[i][0], bb[i]);
            cur1[i][1] = __fadd_rn(cur1[i][1], bb[i]);
        }
    }
    __syncthreads();   // xT fully consumed; its region may be reused

    // ---- prologue step 3: stage W3 (transposed, padded to 8) + biases ----
    for (int idx = t; idx < 640; idx += 512) {
        int o = idx >> 7;             // W3 is [5][128]
        int j = idx & 127;
        W3L[j * 8 + o] = W3[idx];
    }
    if (t < 128) bL[t] = b2g[t];
    if (t < 5)   bL[128 + t] = b3[t];
    __syncthreads();   // W3L/bL staged

    // ---- persistent state (identical to R5) ----
    float m1[16][2];
    #pragma unroll
    for (int i = 0; i < 16; ++i) { m1[i][0] = 0.0f; m1[i][1] = 0.0f; }
    float m2[4][4];                   // [m-tile][reg]
    #pragma unroll
    for (int mt = 0; mt < 4; ++mt)
        #pragma unroll
        for (int rg = 0; rg < 4; ++rg) m2[mt][rg] = 0.0f;
    float m3 = 0.0f, acc3 = 0.0f;

    const unsigned short* fb = W2F + (wv * 24) * 512 + lane * 8;
    const int keyB   = (lane & 7) << 4;   // s1 fragment-read swizzle key
    const int chunkq = lq << 4;
    const int jC     = wv * 16 + l15;     // this lane's layer-2 neuron
    const int keyC2  = ((jC >> 2) & 7) << 3;

    #pragma unroll 1
    for (int stp = 0; stp < NSTEP; ++stp) {
        // ========== A: layer-1 LIF + bf16 spikes -> LDS (identical to R5) ===
        {
            unsigned int dwa[2][8];
            #pragma unroll
            for (int i = 0; i < 16; ++i) {
                #pragma unroll
                for (int s = 0; s < 2; ++s) {
                    float m = m1[i][s];
                    float r = (m > 1.0f) ? 1.0f : 0.0f;
                    m = __fsub_rn(__fadd_rn(__fmul_rn(0.9f, m), cur1[i][s]), r);
                    m1[i][s] = m;
                    unsigned int bits = (m > 1.0f) ? 0x3F80u : 0u;  // bf16 1.0
                    if (i & 1) dwa[s][i >> 1] |= bits << 16;
                    else       dwa[s][i >> 1]  = bits;
                }
            }
            #pragma unroll
            for (int s = 0; s < 2; ++s) {
                const int row = s0a + s;
                const int key = row & 7;
                char* rp = s1bf + row * 512;
                uint4 lo = make_uint4(dwa[s][0], dwa[s][1], dwa[s][2], dwa[s][3]);
                uint4 hi = make_uint4(dwa[s][4], dwa[s][5], dwa[s][6], dwa[s][7]);
                *(uint4*)(rp + (((2 * nt + 0) ^ key) << 4)) = lo;
                *(uint4*)(rp + (((2 * nt + 1) ^ key) << 4)) = hi;
            }
        }
        __syncthreads();   // bar1: s1 ready

        // ========== B: cur2 = s1 @ W2.T via MFMA (identical to R5) ==========
        f32x4 acc[4];
        {
            const f32x4 z = {0.0f, 0.0f, 0.0f, 0.0f};
            acc[0] = z; acc[1] = z; acc[2] = z; acc[3] = z;
        }
        #pragma unroll
        for (int slab = 0; slab < 8; ++slab) {
            const bf16x8 B2 = *(const bf16x8*)(fb + (16 + slab) * 512); // h3
            const bf16x8 B1 = *(const bf16x8*)(fb + (8  + slab) * 512); // h2
            const bf16x8 B0 = *(const bf16x8*)(fb + (0  + slab) * 512); // h1
            const int coff = (slab * 64 + chunkq) ^ keyB;
            const bf16x8 A0 = *(const bf16x8*)(s1bf + (l15     ) * 512 + coff);
            const bf16x8 A1 = *(const bf16x8*)(s1bf + (l15 + 16) * 512 + coff);
            const bf16x8 A2 = *(const bf16x8*)(s1bf + (l15 + 32) * 512 + coff);
            const bf16x8 A3 = *(const bf16x8*)(s1bf + (l15 + 48) * 512 + coff);
            acc[0] = __builtin_amdgcn_mfma_f32_16x16x32_bf16(A0, B2, acc[0], 0, 0, 0);
            acc[1] = __builtin_amdgcn_mfma_f32_16x16x32_bf16(A1, B2, acc[1], 0, 0, 0);
            acc[2] = __builtin_amdgcn_mfma_f32_16x16x32_bf16(A2, B2, acc[2], 0, 0, 0);
            acc[3] = __builtin_amdgcn_mfma_f32_16x16x32_bf16(A3, B2, acc[3], 0, 0, 0);
            acc[0] = __builtin_amdgcn_mfma_f32_16x16x32_bf16(A0, B1, acc[0], 0, 0, 0);
            acc[1] = __builtin_amdgcn_mfma_f32_16x16x32_bf16(A1, B1, acc[1], 0, 0, 0);
            acc[2] = __builtin_amdgcn_mfma_f32_16x16x32_bf16(A2, B1, acc[2], 0, 0, 0);
            acc[3] = __builtin_amdgcn_mfma_f32_16x16x32_bf16(A3, B1, acc[3], 0, 0, 0);
            acc[0] = __builtin_amdgcn_mfma_f32_16x16x32_bf16(A0, B0, acc[0], 0, 0, 0);
            acc[1] = __builtin_amdgcn_mfma_f32_16x16x32_bf16(A1, B0, acc[1], 0, 0, 0);
            acc[2] = __builtin_amdgcn_mfma_f32_16x16x32_bf16(A2, B0, acc[2], 0, 0, 0);
            acc[3] = __builtin_amdgcn_mfma_f32_16x16x32_bf16(A3, B0, acc[3], 0, 0, 0);
        }

        // ========== C: layer-2 LIF + u8 spikes -> LDS (identical to R5) =====
        {
            const float bj = bL[jC];
            #pragma unroll
            for (int mt = 0; mt < 4; ++mt) {
                unsigned int pk = 0;
                #pragma unroll
                for (int rg = 0; rg < 4; ++rg) {
                    float c2 = __fadd_rn(acc[mt][rg], bj);
                    float m = m2[mt][rg];
                    float r = (m > 1.0f) ? 1.0f : 0.0f;
                    m = __fsub_rn(__fadd_rn(__fmul_rn(0.9f, m), c2), r);
                    m2[mt][rg] = m;
                    if (m > 1.0f) pk |= 1u << (8 * rg);
                }
                const int smp0 = mt * 16 + lq * 4;
                *(unsigned int*)&s2Lb[jC * 72 + (smp0 ^ keyC2)] = pk;
            }
        }
        __syncthreads();   // bar2: s2 ready

        // ========== D: layer-3 partial dots (identical to R5) ==========
        if (t < 256) {
            const int sl = t & 63;
            const int jr = t >> 6;
            float part[5] = {0.0f, 0.0f, 0.0f, 0.0f, 0.0f};
            #pragma unroll 8
            for (int jj = 0; jj < 32; ++jj) {
                const int j = jr * 32 + jj;
                const float s2v =
                    (float)s2Lb[j * 72 + (sl ^ (((j >> 2) & 7) << 3))];
                const float4 w3a = *(const float4*)&W3L[j * 8];
                const float  w3e = W3L[j * 8 + 4];
                part[0] = fmaf(w3a.x, s2v, part[0]);
                part[1] = fmaf(w3a.y, s2v, part[1]);
                part[2] = fmaf(w3a.z, s2v, part[2]);
                part[3] = fmaf(w3a.w, s2v, part[3]);
                part[4] = fmaf(w3e,   s2v, part[4]);
            }
            #pragma unroll
            for (int o = 0; o < 5; ++o)
                pL[(o * 4 + jr) * 64 + sl] = part[o];
        }
        __syncthreads();   // bar3: partials ready

        // ========== E: layer-3 LIF + spike count (identical to R5) ==========
        if (t < 320) {
            const int o  = t >> 6;
            const int sl = t & 63;
            float c3 = pL[(o * 4 + 0) * 64 + sl];
            c3 += pL[(o * 4 + 1) * 64 + sl];
            c3 += pL[(o * 4 + 2) * 64 + sl];
            c3 += pL[(o * 4 + 3) * 64 + sl];
            c3 = __fadd_rn(c3, bL[128 + o]);
            float m = m3;
            float r = (m > 1.0f) ? 1.0f : 0.0f;
            m = __fsub_rn(__fadd_rn(__fmul_rn(0.9f, m), c3), r);
            m3 = m;
            if (m > 1.0f) acc3 += 1.0f;
        }
    }

    // ---- epilogue ----
    if (t < 320) {
        out[(sBase + (t & 63)) * 5 + (t >> 6)] = acc3;
    }
}

extern "C" void kernel_launch(void* const* d_in, const int* in_sizes, int n_in,
                              void* d_out, int out_size, void* d_ws, size_t ws_size,
                              hipStream_t stream) {
    const float* x  = (const float*)d_in[0];
    const float* W1 = (const float*)d_in[1];
    const float* b1 = (const float*)d_in[2];
    const float* W2 = (const float*)d_in[3];
    const float* b2 = (const float*)d_in[4];
    const float* W3 = (const float*)d_in[5];
    const float* b3 = (const float*)d_in[6];
    float* out = (float*)d_out;

    float* W1T = (float*)d_ws;                                     // 256 KB
    unsigned short* W2F = (unsigned short*)((char*)d_ws + 262144); // 192 KB

    const int B = in_sizes[0] / 250;      // 131072
    const int nwg = B / 64;               // 2048

    snn_prep <<<64, 256, 0, stream>>>(W1, W1T);
    snn_prep2<<<48, 256, 0, stream>>>(W2, W2F);
    snn_main <<<nwg, 512, 0, stream>>>(x, b1, b2, W3, b3, W1T, W2F, out);
}